// Round 2
// 371.488 us; speedup vs baseline: 1.0834x; 1.0834x over previous
//
#include <hip/hip_runtime.h>

#define FI 256
#define FH 64
#define FO 128
#define ASORT_CHUNK 2048
// ushort-view row stride 256: bf16 h1 at ushort[128..191], bf16 hrelu at [192..255],
// fp32 combined at float[0..63].

__device__ __forceinline__ ushort f2bf(float x) {   // fp32 -> bf16 RNE
    unsigned b = __float_as_uint(x);
    b += 0x7fffu + ((b >> 16) & 1u);
    return (ushort)(b >> 16);
}
__device__ __forceinline__ float bf2f(ushort u) {
    return __uint_as_float(((unsigned)u) << 16);
}

// ---------------- common small kernels ----------------

__global__ void zero_i32(int* __restrict__ p, int n) {
    int i = blockIdx.x * 256 + threadIdx.x;
    if (i < n) p[i] = 0;
}

__global__ void deg_cnt_kernel(const int* __restrict__ dst, int* __restrict__ cnt, int E) {
    int base = blockIdx.x * 1024 + threadIdx.x;
    #pragma unroll
    for (int q = 0; q < 4; ++q) {
        int e = base + q * 256;
        if (e < E) atomicAdd(&cnt[dst[e]], 1);
    }
}

__global__ void dinv_kernel(const int* __restrict__ cnt, float* __restrict__ dinv, int N) {
    int i = blockIdx.x * 256 + threadIdx.x;
    if (i < N) dinv[i] = rsqrtf((float)cnt[i] + 1.0f);
}

// ---------------- CSR build: scan + two-pass binned counting sort ----------------

__global__ void scan_block_kernel(const int* __restrict__ cnt, int* __restrict__ row_start,
                                  int* __restrict__ blksum, int N) {
    __shared__ int sh[256];
    int base = blockIdx.x * 1024 + threadIdx.x * 4;
    int v0 = 0, v1 = 0, v2 = 0, v3 = 0;
    if (base + 0 < N) v0 = cnt[base + 0];
    if (base + 1 < N) v1 = cnt[base + 1];
    if (base + 2 < N) v2 = cnt[base + 2];
    if (base + 3 < N) v3 = cnt[base + 3];
    sh[threadIdx.x] = v0 + v1 + v2 + v3;
    __syncthreads();
    for (int off = 1; off < 256; off <<= 1) {
        int t = (threadIdx.x >= off) ? sh[threadIdx.x - off] : 0;
        __syncthreads();
        sh[threadIdx.x] += t;
        __syncthreads();
    }
    int run = (threadIdx.x > 0) ? sh[threadIdx.x - 1] : 0;
    if (base + 0 < N) row_start[base + 0] = run; run += v0;
    if (base + 1 < N) row_start[base + 1] = run; run += v1;
    if (base + 2 < N) row_start[base + 2] = run; run += v2;
    if (base + 3 < N) row_start[base + 3] = run;
    if (threadIdx.x == 255) blksum[blockIdx.x] = sh[255];
}

__global__ void scan_top_kernel(int* __restrict__ blksum, int nb) {
    if (threadIdx.x == 0 && blockIdx.x == 0) {
        int acc = 0;
        for (int b = 0; b < nb; ++b) { int v = blksum[b]; blksum[b] = acc; acc += v; }
    }
}

// row_start finalize; also seed bucket tails: bucket b covers dst [b*256, b*256+255].
__global__ void scan_add_kernel(int* __restrict__ row_start, int* __restrict__ bucket_pos,
                                const int* __restrict__ blksum, int N) {
    int i = blockIdx.x * 256 + threadIdx.x;
    if (i < N) {
        int v = row_start[i] + blksum[i >> 10];
        row_start[i] = v;
        if ((i & 255) == 0) bucket_pos[i >> 8] = v;
    }
}

// Pass A: per-block LDS counting sort by bucket (dst>>8), flushed as contiguous runs
// into the bucket's final CSR-aligned region. Record packs src|dst<<16 (4B, N<=65536).
__global__ __launch_bounds__(256) void binA_kernel(const int* __restrict__ src,
                                                   const int* __restrict__ dst,
                                                   int* __restrict__ bucket_pos,
                                                   unsigned* __restrict__ binned, int E) {
    __shared__ int lcnt[256];
    __shared__ int lbase[256];
    __shared__ int gbase[256];
    __shared__ int sc[256];
    __shared__ unsigned sorted[ASORT_CHUNK];
    int t = threadIdx.x;
    int base = blockIdx.x * ASORT_CHUNK;
    lcnt[t] = 0;
    __syncthreads();
    unsigned pk[8];
    short bb[8];
    short mi[8];
    #pragma unroll
    for (int j = 0; j < 8; ++j) {
        int e = base + j * 256 + t;
        if (e < E) {
            unsigned s = (unsigned)src[e];
            unsigned d = (unsigned)dst[e];
            pk[j] = s | (d << 16);
            int b = (int)(d >> 8);
            bb[j] = (short)b;
            mi[j] = (short)atomicAdd(&lcnt[b], 1);
        } else {
            bb[j] = -1;
        }
    }
    __syncthreads();
    int v = lcnt[t];
    sc[t] = v;
    __syncthreads();
    #pragma unroll
    for (int off = 1; off < 256; off <<= 1) {
        int u = (t >= off) ? sc[t - off] : 0;
        __syncthreads();
        sc[t] += u;
        __syncthreads();
    }
    lbase[t] = sc[t] - v;                       // exclusive prefix
    if (v > 0) gbase[t] = atomicAdd(&bucket_pos[t], v);
    __syncthreads();
    #pragma unroll
    for (int j = 0; j < 8; ++j)
        if (bb[j] >= 0) sorted[lbase[(int)bb[j]] + (int)mi[j]] = pk[j];
    int tot = sc[255];
    __syncthreads();
    for (int i = t; i < tot; i += 256) {
        unsigned vv = sorted[i];
        int b = (int)(vv >> 24);                // dst>>8 (dst < 65536)
        binned[gbase[b] + (i - lbase[b])] = vv;
    }
}

// Pass B: one block per bucket. Per-node tails live in LDS; writes land in the
// bucket's ~32KB CSR region (full-line write-back, single CU). rec4[p] = src.
__global__ __launch_bounds__(256) void binB_kernel(const int* __restrict__ row_start,
                                                   const unsigned* __restrict__ binned,
                                                   int* __restrict__ rec4, int N, int E) {
    __shared__ int loff[256];
    __shared__ int lstart[256];
    int t = threadIdx.x;
    int d0 = blockIdx.x << 8;
    loff[t] = 0;
    lstart[t] = (d0 + t < N) ? row_start[d0 + t] : E;
    __syncthreads();
    int start = lstart[0];
    int end = (d0 + 256 < N) ? row_start[d0 + 256] : E;
    int i = start + t;
    for (; i + 768 < end; i += 1024) {
        unsigned v0 = binned[i];
        unsigned v1 = binned[i + 256];
        unsigned v2 = binned[i + 512];
        unsigned v3 = binned[i + 768];
        int dA = (int)((v0 >> 16) & 0xffu); int kA = atomicAdd(&loff[dA], 1);
        rec4[lstart[dA] + kA] = (int)(v0 & 0xffffu);
        int dB = (int)((v1 >> 16) & 0xffu); int kB = atomicAdd(&loff[dB], 1);
        rec4[lstart[dB] + kB] = (int)(v1 & 0xffffu);
        int dC = (int)((v2 >> 16) & 0xffu); int kC = atomicAdd(&loff[dC], 1);
        rec4[lstart[dC] + kC] = (int)(v2 & 0xffffu);
        int dD = (int)((v3 >> 16) & 0xffu); int kD = atomicAdd(&loff[dD], 1);
        rec4[lstart[dD] + kD] = (int)(v3 & 0xffffu);
    }
    for (; i < end; i += 256) {
        unsigned v = binned[i];
        int d = (int)((v >> 16) & 0xffu);
        int k = atomicAdd(&loff[d], 1);
        rec4[lstart[d] + k] = (int)(v & 0xffffu);
    }
}

// ---------------- gather-side aggregation: 4 edges per wave-instruction ----------------
// Wave = 1 node. Lane L: g = L>>4 (edge slot), q = L&15 (feature quad, 4 bf16 = 8B).
// rec4 holds src only; w = dinv[src]*dinv[node] recomputed (dinv is L2-resident).

// layer 1: gather bf16 h1 (cols [128..191]); write bf16 hrelu = relu(acc + dv^2*own + b1)
__global__ void gather_relu_kernel(const int* __restrict__ rec4, const int* __restrict__ row_start,
                                   const int* __restrict__ cnt, const float* __restrict__ dinv,
                                   const float* __restrict__ b1, float* __restrict__ out, int N) {
    int node = blockIdx.x * 4 + (threadIdx.x >> 6);
    if (node >= N) return;
    int L = threadIdx.x & 63;
    int g = L >> 4;
    int q = L & 15;
    const ushort* hb = (const ushort*)out;
    int beg = row_start[node];
    int n   = cnt[node];
    float dvd = dinv[node];
    float4 acc = make_float4(0.f, 0.f, 0.f, 0.f);
    for (int i = 0; i < n; i += 16) {
        #pragma unroll
        for (int u = 0; u < 4; ++u) {
            int idx = i + u * 4 + g;
            int sidx = node;
            float w = 0.f;
            if (idx < n) {
                sidx = rec4[beg + idx];
                w = dinv[sidx] * dvd;
            }
            uint2 hv = *(const uint2*)(hb + (size_t)sidx * 256 + 128 + q * 4);
            acc.x = fmaf(bf2f((ushort)(hv.x & 0xffffu)), w, acc.x);
            acc.y = fmaf(bf2f((ushort)(hv.x >> 16)),     w, acc.y);
            acc.z = fmaf(bf2f((ushort)(hv.y & 0xffffu)), w, acc.z);
            acc.w = fmaf(bf2f((ushort)(hv.y >> 16)),     w, acc.w);
        }
    }
    acc.x += __shfl_xor(acc.x, 16, 64);
    acc.y += __shfl_xor(acc.y, 16, 64);
    acc.z += __shfl_xor(acc.z, 16, 64);
    acc.w += __shfl_xor(acc.w, 16, 64);
    acc.x += __shfl_xor(acc.x, 32, 64);
    acc.y += __shfl_xor(acc.y, 32, 64);
    acc.z += __shfl_xor(acc.z, 32, 64);
    acc.w += __shfl_xor(acc.w, 32, 64);
    if (L < 16) {
        float dv2 = dvd * dvd;
        uint2 ho = *(const uint2*)(hb + (size_t)node * 256 + 128 + q * 4);
        float4 b = *(const float4*)&b1[q * 4];
        float r0 = fmaxf(acc.x + dv2 * bf2f((ushort)(ho.x & 0xffffu)) + b.x, 0.f);
        float r1 = fmaxf(acc.y + dv2 * bf2f((ushort)(ho.x >> 16))     + b.y, 0.f);
        float r2 = fmaxf(acc.z + dv2 * bf2f((ushort)(ho.y & 0xffffu)) + b.z, 0.f);
        float r3 = fmaxf(acc.w + dv2 * bf2f((ushort)(ho.y >> 16))     + b.w, 0.f);
        ushort4 st = {f2bf(r0), f2bf(r1), f2bf(r2), f2bf(r3)};
        *(ushort4*)((ushort*)out + (size_t)node * 256 + 192 + q * 4) = st;
    }
}

// layer 2: gather bf16 hrelu (cols [192..255]); write fp32 combined to float[0..63]
__global__ void gather_comb_kernel(const int* __restrict__ rec4, const int* __restrict__ row_start,
                                   const int* __restrict__ cnt, const float* __restrict__ dinv,
                                   float* __restrict__ out, int N) {
    int node = blockIdx.x * 4 + (threadIdx.x >> 6);
    if (node >= N) return;
    int L = threadIdx.x & 63;
    int g = L >> 4;
    int q = L & 15;
    const ushort* hb = (const ushort*)out;
    int beg = row_start[node];
    int n   = cnt[node];
    float dvd = dinv[node];
    float4 acc = make_float4(0.f, 0.f, 0.f, 0.f);
    for (int i = 0; i < n; i += 16) {
        #pragma unroll
        for (int u = 0; u < 4; ++u) {
            int idx = i + u * 4 + g;
            int sidx = node;
            float w = 0.f;
            if (idx < n) {
                sidx = rec4[beg + idx];
                w = dinv[sidx] * dvd;
            }
            uint2 hv = *(const uint2*)(hb + (size_t)sidx * 256 + 192 + q * 4);
            acc.x = fmaf(bf2f((ushort)(hv.x & 0xffffu)), w, acc.x);
            acc.y = fmaf(bf2f((ushort)(hv.x >> 16)),     w, acc.y);
            acc.z = fmaf(bf2f((ushort)(hv.y & 0xffffu)), w, acc.z);
            acc.w = fmaf(bf2f((ushort)(hv.y >> 16)),     w, acc.w);
        }
    }
    acc.x += __shfl_xor(acc.x, 16, 64);
    acc.y += __shfl_xor(acc.y, 16, 64);
    acc.z += __shfl_xor(acc.z, 16, 64);
    acc.w += __shfl_xor(acc.w, 16, 64);
    acc.x += __shfl_xor(acc.x, 32, 64);
    acc.y += __shfl_xor(acc.y, 32, 64);
    acc.z += __shfl_xor(acc.z, 32, 64);
    acc.w += __shfl_xor(acc.w, 32, 64);
    if (L < 16) {
        float dv2 = dvd * dvd;
        uint2 ho = *(const uint2*)(hb + (size_t)node * 256 + 192 + q * 4);
        float4 o;
        o.x = acc.x + dv2 * bf2f((ushort)(ho.x & 0xffffu));
        o.y = acc.y + dv2 * bf2f((ushort)(ho.x >> 16));
        o.z = acc.z + dv2 * bf2f((ushort)(ho.y & 0xffffu));
        o.w = acc.w + dv2 * bf2f((ushort)(ho.y >> 16));
        *(float4*)&out[(size_t)node * FO + q * 4] = o;
    }
}

// ---------------- dense kernels: register-tiled SGEMM ----------------

// mm1: h1 = x @ W1 -> bf16 at ushort[128..191] of each row (plain, unscaled).
__global__ __launch_bounds__(256) void mm1_tiled(const float* __restrict__ x,
                                                 const float* __restrict__ W1,
                                                 float* __restrict__ out, int N) {
    __shared__ float xs[32][128];
    __shared__ float ws[32][64];
    int tid = threadIdx.x;
    int R0  = blockIdx.x * 128;
    int ty  = tid >> 3;
    int tx  = tid & 7;
    float acc[4][8];
    #pragma unroll
    for (int i = 0; i < 4; ++i)
        #pragma unroll
        for (int j = 0; j < 8; ++j) acc[i][j] = 0.f;

    int sr = tid >> 1;
    int sk = (tid & 1) * 16;
    bool row_ok = (R0 + sr) < N;
    const float* xrow = x + (size_t)(R0 + sr) * FI;

    for (int k0 = 0; k0 < FI; k0 += 32) {
        __syncthreads();
        #pragma unroll
        for (int q = 0; q < 4; ++q) {
            float4 v = row_ok ? *(const float4*)&xrow[k0 + sk + q * 4]
                              : make_float4(0.f, 0.f, 0.f, 0.f);
            xs[sk + q * 4 + 0][sr] = v.x;
            xs[sk + q * 4 + 1][sr] = v.y;
            xs[sk + q * 4 + 2][sr] = v.z;
            xs[sk + q * 4 + 3][sr] = v.w;
        }
        {
            int f = tid * 2;
            *(float4*)&ws[0][0 + f * 4]     = *(const float4*)&W1[(size_t)k0 * 64 + f * 4];
            *(float4*)&ws[0][0 + f * 4 + 4] = *(const float4*)&W1[(size_t)k0 * 64 + f * 4 + 4];
        }
        __syncthreads();
        #pragma unroll 4
        for (int k = 0; k < 32; ++k) {
            float4 a  = *(const float4*)&xs[k][ty * 4];
            float4 bl = *(const float4*)&ws[k][tx * 4];
            float4 bh = *(const float4*)&ws[k][32 + tx * 4];
            float av[4] = {a.x, a.y, a.z, a.w};
            float bv[8] = {bl.x, bl.y, bl.z, bl.w, bh.x, bh.y, bh.z, bh.w};
            #pragma unroll
            for (int i = 0; i < 4; ++i)
                #pragma unroll
                for (int j = 0; j < 8; ++j)
                    acc[i][j] = fmaf(av[i], bv[j], acc[i][j]);
        }
    }
    #pragma unroll
    for (int i = 0; i < 4; ++i) {
        int row = R0 + ty * 4 + i;
        if (row < N) {
            ushort* ob = (ushort*)out + (size_t)row * 256 + 128;
            ushort4 lo = {f2bf(acc[i][0]), f2bf(acc[i][1]), f2bf(acc[i][2]), f2bf(acc[i][3])};
            ushort4 hi = {f2bf(acc[i][4]), f2bf(acc[i][5]), f2bf(acc[i][6]), f2bf(acc[i][7])};
            *(ushort4*)&ob[tx * 4]      = lo;
            *(ushort4*)&ob[32 + tx * 4] = hi;
        }
    }
}

// mm2: out_row = combined(float[0..63]) @ W2 + b2, in place.
__global__ __launch_bounds__(256) void mm2_tiled(const float* __restrict__ W2,
                                                 const float* __restrict__ b2,
                                                 float* __restrict__ out, int N) {
    __shared__ float xs[64][68];
    __shared__ float ws[64][128];
    int tid = threadIdx.x;
    int R0  = blockIdx.x * 64;
    int ty  = tid >> 4;
    int tx  = tid & 15;

    {
        int sr = tid >> 2;
        int l4 = tid & 3;
        int grow = R0 + sr;
        bool ok = grow < N;
        const float* orow = out + (size_t)grow * FO;
        #pragma unroll
        for (int q = 0; q < 4; ++q) {
            int j0 = (l4 + 4 * q) * 4;
            float4 a = ok ? *(const float4*)&orow[j0] : make_float4(0.f, 0.f, 0.f, 0.f);
            xs[j0 + 0][sr] = a.x;
            xs[j0 + 1][sr] = a.y;
            xs[j0 + 2][sr] = a.z;
            xs[j0 + 3][sr] = a.w;
        }
    }
    #pragma unroll
    for (int q = 0; q < 8; ++q) {
        int f = tid + q * 256;
        *(float4*)&ws[f >> 5][(f & 31) * 4] = *(const float4*)&W2[(size_t)f * 4];
    }
    __syncthreads();

    float acc[4][8];
    #pragma unroll
    for (int i = 0; i < 4; ++i)
        #pragma unroll
        for (int j = 0; j < 8; ++j) acc[i][j] = 0.f;

    #pragma unroll 4
    for (int k = 0; k < FH; ++k) {
        float4 a  = *(const float4*)&xs[k][ty * 4];
        float4 bl = *(const float4*)&ws[k][tx * 4];
        float4 bh = *(const float4*)&ws[k][64 + tx * 4];
        float av[4] = {a.x, a.y, a.z, a.w};
        float bv[8] = {bl.x, bl.y, bl.z, bl.w, bh.x, bh.y, bh.z, bh.w};
        #pragma unroll
        for (int i = 0; i < 4; ++i)
            #pragma unroll
            for (int j = 0; j < 8; ++j)
                acc[i][j] = fmaf(av[i], bv[j], acc[i][j]);
    }

    float4 b2l = *(const float4*)&b2[tx * 4];
    float4 b2h = *(const float4*)&b2[64 + tx * 4];
    #pragma unroll
    for (int i = 0; i < 4; ++i) {
        int row = R0 + ty * 4 + i;
        if (row < N) {
            float* o = out + (size_t)row * FO;
            *(float4*)&o[tx * 4] = make_float4(acc[i][0] + b2l.x, acc[i][1] + b2l.y,
                                               acc[i][2] + b2l.z, acc[i][3] + b2l.w);
            *(float4*)&o[64 + tx * 4] = make_float4(acc[i][4] + b2h.x, acc[i][5] + b2h.y,
                                                    acc[i][6] + b2h.z, acc[i][7] + b2h.w);
        }
    }
}

// ---------------- fallback (atomic scatter) pieces — all fp32 ----------------

__global__ void expand_hs1_kernel(float* __restrict__ out, int N) {
    int row = blockIdx.x * 4 + (threadIdx.x >> 6);
    if (row >= N) return;
    int lane = threadIdx.x & 63;
    float v = bf2f(((const ushort*)out)[(size_t)row * 256 + 128 + lane]);
    out[(size_t)row * FO + FH + lane] = v;
}

__global__ void zero_half_kernel(float* __restrict__ out, int half, int N) {
    int i = blockIdx.x * 256 + threadIdx.x;
    if (i >= N * FH) return;
    out[(size_t)(i >> 6) * FO + half + (i & 63)] = 0.f;
}

__global__ void scatter_half_kernel(const int* __restrict__ src, const int* __restrict__ dst,
                                    const float* __restrict__ dinv, float* __restrict__ out,
                                    int rh, int wh, int E) {
    int e = blockIdx.x * 4 + (threadIdx.x >> 6);
    if (e >= E) return;
    int lane = threadIdx.x & 63;
    int s = src[e];
    int d = dst[e];
    float w = dinv[s] * dinv[d];
    atomicAdd(&out[(size_t)d * FO + wh + lane], out[(size_t)s * FO + rh + lane] * w);
}

// lower = relu(lower_agg + dv^2*upper_own + b1)
__global__ void finish1_kernel(float* __restrict__ out, const float* __restrict__ dinv,
                               const float* __restrict__ b1, int N) {
    int i = blockIdx.x * 256 + threadIdx.x;
    if (i >= N * FH) return;
    int row = i >> 6;
    int c   = i & 63;
    size_t base = (size_t)row * FO;
    float dv = dinv[row];
    out[base + c] = fmaxf(out[base + c] + dv * dv * out[base + FH + c] + b1[c], 0.f);
}

// lower = upper_agg + dv^2*lower_own   (combined for mm2)
__global__ void finish2_kernel(float* __restrict__ out, const float* __restrict__ dinv, int N) {
    int i = blockIdx.x * 256 + threadIdx.x;
    if (i >= N * FH) return;
    int row = i >> 6;
    int c   = i & 63;
    size_t base = (size_t)row * FO;
    float dv = dinv[row];
    out[base + c] = out[base + FH + c] + dv * dv * out[base + c];
}

extern "C" void kernel_launch(void* const* d_in, const int* in_sizes, int n_in,
                              void* d_out, int out_size, void* d_ws, size_t ws_size,
                              hipStream_t stream) {
    const float* x  = (const float*)d_in[0];
    const int*   ei = (const int*)d_in[1];
    const float* W1 = (const float*)d_in[2];
    const float* b1 = (const float*)d_in[3];
    const float* W2 = (const float*)d_in[4];
    const float* b2 = (const float*)d_in[5];
    float* out = (float*)d_out;

    int N = in_sizes[0] / FI;     // 50000
    int E = in_sizes[1] / 2;      // 1600000
    const int* src = ei;
    const int* dst = ei + E;

    char* w = (char*)d_ws;
    float* dinv       = (float*)w;      w += (size_t)N * 4;
    int*   cnt        = (int*)w;        w += (size_t)N * 4;
    int*   row_start  = (int*)w;        w += (size_t)N * 4;
    int*   blksum     = (int*)w;        w += 256 * 4;
    int*   bucket_pos = (int*)w;        w += 256 * 4;
    unsigned* binned  = (unsigned*)w;   w += (size_t)E * 4;
    int*   rec4       = (int*)w;        w += (size_t)E * 4;
    size_t need = (size_t)(w - (char*)d_ws);   // ~13.4 MB (within the 13.6 MB proven in r5)

    int nb  = (N + 1023) / 1024;
    int nbk = (N + 255) >> 8;     // buckets of 256 dst nodes (196 for N=50000)

    zero_i32<<<(N + 255) / 256, 256, 0, stream>>>(cnt, N);
    deg_cnt_kernel<<<(E + 1023) / 1024, 256, 0, stream>>>(dst, cnt, E);
    dinv_kernel<<<(N + 255) / 256, 256, 0, stream>>>(cnt, dinv, N);

    if (ws_size >= need && N <= 65536) {
        scan_block_kernel<<<nb, 256, 0, stream>>>(cnt, row_start, blksum, N);
        scan_top_kernel<<<1, 64, 0, stream>>>(blksum, nb);
        scan_add_kernel<<<(N + 255) / 256, 256, 0, stream>>>(row_start, bucket_pos, blksum, N);
        binA_kernel<<<(E + ASORT_CHUNK - 1) / ASORT_CHUNK, 256, 0, stream>>>(src, dst, bucket_pos, binned, E);
        binB_kernel<<<nbk, 256, 0, stream>>>(row_start, binned, rec4, N, E);

        mm1_tiled<<<(N + 127) / 128, 256, 0, stream>>>(x, W1, out, N);
        gather_relu_kernel<<<(N + 3) / 4, 256, 0, stream>>>(rec4, row_start, cnt, dinv, b1, out, N);
        gather_comb_kernel<<<(N + 3) / 4, 256, 0, stream>>>(rec4, row_start, cnt, dinv, out, N);
        mm2_tiled<<<(N + 63) / 64, 256, 0, stream>>>(W2, b2, out, N);
    } else {
        // fallback: atomic scatter path, all fp32
        mm1_tiled<<<(N + 127) / 128, 256, 0, stream>>>(x, W1, out, N);
        expand_hs1_kernel<<<(N + 3) / 4, 256, 0, stream>>>(out, N);
        zero_half_kernel<<<((N * FH) + 255) / 256, 256, 0, stream>>>(out, 0, N);
        scatter_half_kernel<<<(E + 3) / 4, 256, 0, stream>>>(src, dst, dinv, out, FH, 0, E);
        finish1_kernel<<<((N * FH) + 255) / 256, 256, 0, stream>>>(out, dinv, b1, N);
        zero_half_kernel<<<((N * FH) + 255) / 256, 256, 0, stream>>>(out, FH, N);
        scatter_half_kernel<<<(E + 3) / 4, 256, 0, stream>>>(src, dst, dinv, out, 0, FH, E);
        finish2_kernel<<<((N * FH) + 255) / 256, 256, 0, stream>>>(out, dinv, N);
        mm2_tiled<<<(N + 63) / 64, 256, 0, stream>>>(W2, b2, out, N);
    }
}